// Round 1
// 638.087 us; speedup vs baseline: 1.0330x; 1.0330x over previous
//
#include <hip/hip_runtime.h>
#include <hip/hip_bf16.h>

#define NB 512
#define KD 128
#define VD 64
#define NKEYS 500000
#define TOPK 16
#define CH 1024
#define NCHUNK 489            // ceil(500000/1024)
#define NCAND (NCHUNK*4)      // 1956 candidates per query
#define CBUF 64               // merge rescore buffer (threshold select keeps 32..64)

typedef __attribute__((ext_vector_type(8))) short bf8s;
typedef __attribute__((ext_vector_type(4))) float f4;

__device__ __forceinline__ unsigned f2bf(float x) {
  union { float f; unsigned u; } v; v.f = x;
  return (v.u + 0x7fffu + ((v.u >> 16) & 1u)) >> 16;   // RNE fp32->bf16
}

// lgkmcnt(0)-only barrier: LDS ordering guaranteed, global prefetch loads
// stay in flight across the barrier (vmcnt NOT drained, unlike __syncthreads)
__device__ __forceinline__ void barrier_lgkm() {
  asm volatile("s_waitcnt lgkmcnt(0)" ::: "memory");
  __builtin_amdgcn_s_barrier();
}

// ---------------- Kernel 1: normalize queries, fold in 1/temperature = 4 ----
__global__ __launch_bounds__(128) void qnorm_kernel(const float* __restrict__ q,
                                                    float* __restrict__ qn_f,
                                                    short* __restrict__ qn_bf) {
  int b = blockIdx.x, t = threadIdx.x;
  float x = q[b*KD + t];
  float s = x * x;
  #pragma unroll
  for (int o = 32; o > 0; o >>= 1) s += __shfl_down(s, o);
  __shared__ float p[2];
  if ((t & 63) == 0) p[t >> 6] = s;
  __syncthreads();
  float norm = sqrtf(p[0] + p[1]);
  norm = fmaxf(norm, 1e-8f);
  float v = x * (4.0f / norm);        // qn * (1/0.25); *4 is exact in fp32
  qn_f[b*KD + t] = v;
  qn_bf[b*KD + t] = (short)f2bf(v);
}

// ---------------- Kernel 2: bf16 MFMA approx scores + per-chunk local top-4 --
// grid = (NCHUNK, 2). Block: 256 threads = 4 waves; each wave owns 64 queries
// (4 MFMA m-tiles), all waves share the same 16-key n-tile per pass.
// Software-pipelined: next tile's global loads issue right after the current
// tile's raw data is consumed by the bf16 convert, and stay outstanding across
// the (lgkm-only) barriers -> ~500-700 cycle latency window per load.
__global__ __launch_bounds__(256) void score_filter_kernel(
    const float* __restrict__ keys, const short* __restrict__ qn_bf,
    float* __restrict__ cand_val, int* __restrict__ cand_idx) {
  __shared__ float slds[256 * 17];           // [256 queries][16 cols], pad 17
  const int chunk = blockIdx.x, gy = blockIdx.y;
  const int tid  = threadIdx.x;
  const int wave = tid >> 6, lane = tid & 63;
  const int col  = lane & 15, quad = lane >> 4;

  // A fragments: A[m = lane&15][k = quad*8 + j], held in regs for whole chunk
  bf8s afrag[4][4];
  const int qbase = gy*256 + wave*64;
  #pragma unroll
  for (int mt = 0; mt < 4; mt++)
    #pragma unroll
    for (int ks = 0; ks < 4; ks++)
      afrag[mt][ks] = *(const bf8s*)(qn_bf + (qbase + mt*16 + col)*KD + ks*32 + quad*8);

  float tv0=-1e30f, tv1=-1e30f, tv2=-1e30f, tv3=-1e30f;
  int   ti0=0, ti1=0, ti2=0, ti3=0;
  const int nchunk0 = chunk * CH;

  // prologue: issue tile-0 loads
  f4 x0[4], x1[4];
  {
    int r = nchunk0 + col; if (r > NKEYS-1) r = NKEYS-1;   // clamp OOB rows
    const float* kp = keys + (size_t)r*KD + quad*8;
    #pragma unroll
    for (int ks = 0; ks < 4; ks++) {
      x0[ks] = *(const f4*)(kp + ks*32);
      x1[ks] = *(const f4*)(kp + ks*32 + 4);
    }
  }

  for (int nt = 0; nt < CH/16; nt++) {
    const int nb = nchunk0 + nt*16;
    // convert current tile (consumes x0/x1): B[k = quad*8+j][n = lane&15]
    bf8s bfrag[4];
    #pragma unroll
    for (int ks = 0; ks < 4; ks++) {
      bf8s tt;
      tt[0]=(short)f2bf(x0[ks][0]); tt[1]=(short)f2bf(x0[ks][1]);
      tt[2]=(short)f2bf(x0[ks][2]); tt[3]=(short)f2bf(x0[ks][3]);
      tt[4]=(short)f2bf(x1[ks][0]); tt[5]=(short)f2bf(x1[ks][1]);
      tt[6]=(short)f2bf(x1[ks][2]); tt[7]=(short)f2bf(x1[ks][3]);
      bfrag[ks] = tt;
    }
    // prefetch next tile into x regs; stays in flight across both barriers
    if (nt + 1 < CH/16) {
      int r = nb + 16 + col; if (r > NKEYS-1) r = NKEYS-1;
      const float* kp = keys + (size_t)r*KD + quad*8;
      #pragma unroll
      for (int ks = 0; ks < 4; ks++) {
        x0[ks] = *(const f4*)(kp + ks*32);
        x1[ks] = *(const f4*)(kp + ks*32 + 4);
      }
    }
    f4 acc[4];
    #pragma unroll
    for (int mt = 0; mt < 4; mt++) { acc[mt][0]=0.f; acc[mt][1]=0.f; acc[mt][2]=0.f; acc[mt][3]=0.f; }
    #pragma unroll
    for (int ks = 0; ks < 4; ks++)
      #pragma unroll
      for (int mt = 0; mt < 4; mt++)
        acc[mt] = __builtin_amdgcn_mfma_f32_16x16x32_bf16(afrag[mt][ks], bfrag[ks], acc[mt], 0, 0, 0);
    // C/D layout: col = lane&15, row = quad*4 + reg  (m89-verified)
    #pragma unroll
    for (int mt = 0; mt < 4; mt++)
      #pragma unroll
      for (int rg = 0; rg < 4; rg++)
        slds[(wave*64 + mt*16 + quad*4 + rg)*17 + col] = acc[mt][rg];
    barrier_lgkm();
    // selection: thread t owns query (gy*256 + t); scan 16 cols
    #pragma unroll
    for (int c = 0; c < 16; c++) {
      int n = nb + c;
      float v = slds[tid*17 + c];
      if (v > tv3 && n < NKEYS) {
        if (v > tv0)      { tv3=tv2;ti3=ti2; tv2=tv1;ti2=ti1; tv1=tv0;ti1=ti0; tv0=v;ti0=n; }
        else if (v > tv1) { tv3=tv2;ti3=ti2; tv2=tv1;ti2=ti1; tv1=v;ti1=n; }
        else if (v > tv2) { tv3=tv2;ti3=ti2; tv2=v;ti2=n; }
        else              { tv3=v;ti3=n; }
      }
    }
    barrier_lgkm();
  }
  const int gq = gy*256 + tid;
  const size_t o = ((size_t)gq*NCHUNK + chunk)*4;
  cand_val[o+0]=tv0; cand_val[o+1]=tv1; cand_val[o+2]=tv2; cand_val[o+3]=tv3;
  cand_idx[o+0]=ti0; cand_idx[o+1]=ti1; cand_idx[o+2]=ti2; cand_idx[o+3]=ti3;
}

// ---------------- Kernel 3: radix threshold-select -> exact fp32 rescore ----
// Replaces 32 sequential block-wide argmax rounds (the ~310us mystery) with a
// 2-3 pass histogram select: find thr with 32 <= |{v >= thr}| <= 64.
// The selected set is a SUPERSET of the old exact-top-32-by-approx-score, so
// the final exact-rescored top-16 is equal or strictly closer to reference.
__global__ __launch_bounds__(256) void merge_rescore_kernel(
    const float* __restrict__ qn_f, const float* __restrict__ keys,
    const float* __restrict__ values, const float* __restrict__ cand_val,
    const int* __restrict__ cand_idx, float* __restrict__ out) {
  const int b = blockIdx.x, t = threadIdx.x;
  const int lane = t & 63, wave = t >> 6;
  __shared__ float qs[KD];
  __shared__ unsigned hist[256];
  __shared__ int wtot[4];
  __shared__ int s_bound, s_above, s_bcnt, s_cnt;
  __shared__ float rv[CBUF]; __shared__ int ri[CBUF];
  __shared__ float sval[TOPK]; __shared__ int sidx[TOPK]; __shared__ float sw[TOPK];

  if (t < KD) qs[t] = qn_f[b*KD + t];

  // per-thread 8 candidates, fp32 value -> order-preserving u32
  unsigned u[8]; int id[8];
  #pragma unroll
  for (int j = 0; j < 8; j++) {
    int i = t + j*256;
    if (i < NCAND) {
      union { float f; unsigned q; } cvt; cvt.f = cand_val[(size_t)b*NCAND + i];
      unsigned m = cvt.q;
      m = (m & 0x80000000u) ? ~m : (m | 0x80000000u);
      u[j] = m; id[j] = cand_idx[(size_t)b*NCAND + i];
    } else { u[j] = 0u; id[j] = -1; }
  }

  // radix threshold select over top 24 bits, 8 bits per pass
  unsigned prefix = 0; int above = 0; unsigned thr = 0; bool done = false;
  #pragma unroll 1
  for (int pass = 0; pass < 3 && !done; pass++) {
    const int shift = 24 - 8*pass;
    hist[t] = 0u;
    __syncthreads();
    #pragma unroll
    for (int j = 0; j < 8; j++) {
      bool ok = (pass == 0) || ((u[j] >> (shift + 8)) == prefix);
      if (ok) atomicAdd(&hist[(u[j] >> shift) & 255u], 1u);
    }
    __syncthreads();
    int h = (int)hist[t];
    // suffix-inclusive sum: within-wave (64 bins) via shuffles, then add
    // totals of higher wave-groups
    int s = h;
    #pragma unroll
    for (int o = 1; o < 64; o <<= 1) {
      int nv = __shfl_down(s, o);
      if (lane + o < 64) s += nv;
    }
    if (lane == 0) wtot[wave] = s;
    __syncthreads();
    int add = 0;
    for (int g = wave + 1; g < 4; g++) add += wtot[g];
    int S = s + add;                          // count of cands with bin >= t
    // unique non-empty boundary bin: rank-32 falls inside it
    if (above + S >= 32 && above + S - h < 32) {
      s_bound = t; s_above = above + S - h; s_bcnt = h;
    }
    __syncthreads();
    prefix = (prefix << 8) | (unsigned)s_bound;
    above  = s_above;
    if (s_above + s_bcnt <= CBUF || pass == 2) { thr = prefix << shift; done = true; }
    __syncthreads();   // all reads of s_*/hist done before next pass reuses them
  }

  // collect ids with u >= thr  (32 <= count <= 64 except impossible tie-storms)
  if (t == 0) s_cnt = 0;
  __syncthreads();
  #pragma unroll
  for (int j = 0; j < 8; j++) {
    if (id[j] >= 0 && u[j] >= thr) {
      int p = atomicAdd(&s_cnt, 1);
      if (p < CBUF) ri[p] = id[j];
    }
  }
  __syncthreads();
  const int C = min(s_cnt, CBUF);
  if (t >= C && t < CBUF) ri[t] = 0x7fffffff;
  __syncthreads();

  // exact fp32 rescore: 4 threads per candidate, 32 dims each
  {
    int c = t >> 2, dg = t & 3;
    float part = 0.f;
    if (c < C) {
      const float* kr = keys + (size_t)ri[c]*KD + dg*32;
      #pragma unroll
      for (int j = 0; j < 32; j++) part += kr[j] * qs[dg*32 + j];
    }
    part += __shfl_down(part, 2, 4);
    part += __shfl_down(part, 1, 4);
    if (dg == 0) rv[c] = (c < C) ? part : -1e30f;
  }
  __syncthreads();

  // exact rank (desc value, tie -> lower index, matching jax.lax.top_k)
  if (t < CBUF) {
    float v = rv[t]; int idx = ri[t];
    int rank = 0;
    for (int j = 0; j < CBUF; j++) {
      float vj = rv[j]; int ij = ri[j];
      rank += (vj > v) || (vj == v && ij < idx);
    }
    if (rank < TOPK) { sval[rank] = v; sidx[rank] = idx; }
  }
  __syncthreads();

  // softmax with +eps denominator; write topw and topidx (as float)
  if (t < TOPK) {
    float m = sval[0];
    float e = expf(sval[t] - m);
    float s2 = e;
    #pragma unroll
    for (int o = 8; o > 0; o >>= 1) s2 += __shfl_down(s2, o, 16);
    s2 = __shfl(s2, 0, 16);
    float w = e / (s2 + 1e-8f);
    sw[t] = w;
    out[NB*VD + b*TOPK + t] = w;                        // topw
    out[NB*VD + NB*TOPK + b*TOPK + t] = (float)sidx[t]; // topidx as float
  }
  __syncthreads();

  // retrieved = sum_k w_k * values[idx_k]
  if (t < VD) {
    float acc = 0.f;
    #pragma unroll
    for (int k = 0; k < TOPK; k++) acc += sw[k] * values[(size_t)sidx[k]*VD + t];
    out[b*VD + t] = acc;
  }
}

extern "C" void kernel_launch(void* const* d_in, const int* in_sizes, int n_in,
                              void* d_out, int out_size, void* d_ws, size_t ws_size,
                              hipStream_t stream) {
  const float* queries = (const float*)d_in[0];
  const float* keys    = (const float*)d_in[1];
  const float* values  = (const float*)d_in[2];
  float* out = (float*)d_out;

  char* ws = (char*)d_ws;
  float* qn_f  = (float*)ws;                                   // 512*128 f32
  short* qn_bf = (short*)(ws + (size_t)NB*KD*4);               // 512*128 bf16
  float* cand_val = (float*)(ws + (size_t)NB*KD*4 + (size_t)NB*KD*2);
  int*   cand_idx = (int*)((char*)cand_val + (size_t)NB*NCHUNK*4*sizeof(float));

  qnorm_kernel<<<NB, KD, 0, stream>>>(queries, qn_f, qn_bf);
  score_filter_kernel<<<dim3(NCHUNK, 2), 256, 0, stream>>>(keys, qn_bf, cand_val, cand_idx);
  merge_rescore_kernel<<<NB, 256, 0, stream>>>(qn_f, keys, values, cand_val, cand_idx, out);
}

// Round 2
// 628.949 us; speedup vs baseline: 1.0480x; 1.0145x over previous
//
#include <hip/hip_runtime.h>
#include <hip/hip_bf16.h>

#define NB 512
#define KD 128
#define VD 64
#define NKEYS 500000
#define TOPK 16
#define CH 1024
#define NCHUNK 489            // ceil(500000/1024)
#define CPC 8                 // candidates kept per (query, chunk)
#define NCAND (NCHUNK*CPC)    // 3912 candidates per query
#define CBUF 64               // merge rescore buffer (threshold select keeps 32..64)
#define JCAND 16              // ceil(NCAND/256) per-thread candidates in merge

typedef __attribute__((ext_vector_type(8))) short bf8s;
typedef __attribute__((ext_vector_type(4))) float f4;
typedef __attribute__((ext_vector_type(4))) int i4;

__device__ __forceinline__ unsigned f2bf(float x) {
  union { float f; unsigned u; } v; v.f = x;
  return (v.u + 0x7fffu + ((v.u >> 16) & 1u)) >> 16;   // RNE fp32->bf16
}

// ---------------- Kernel 1: normalize queries, fold in 1/temperature = 4 ----
__global__ __launch_bounds__(128) void qnorm_kernel(const float* __restrict__ q,
                                                    float* __restrict__ qn_f,
                                                    short* __restrict__ qn_bf) {
  int b = blockIdx.x, t = threadIdx.x;
  float x = q[b*KD + t];
  float s = x * x;
  #pragma unroll
  for (int o = 32; o > 0; o >>= 1) s += __shfl_down(s, o);
  __shared__ float p[2];
  if ((t & 63) == 0) p[t >> 6] = s;
  __syncthreads();
  float norm = sqrtf(p[0] + p[1]);
  norm = fmaxf(norm, 1e-8f);
  float v = x * (4.0f / norm);        // qn * (1/0.25); *4 is exact in fp32
  qn_f[b*KD + t] = v;
  qn_bf[b*KD + t] = (short)f2bf(v);
}

// ---------------- Kernel 2: barrier-free MFMA scores + per-chunk top-8 ------
// Grid: 1-D, 62*64 blocks. Mapping groups the 8 blocks of one chunk onto the
// same XCD residue (chunk = bid%8 + 8*(bid/64), gy = (bid/8)%8) so the XCD's
// L2 dedups the 8x key re-read.
// Block: 256 threads = 4 waves; block owns 64 queries (gy), each wave owns a
// DISJOINT 256-key quarter of the chunk -> no cross-wave data sharing -> the
// main loop has NO barriers. Each wave: load+convert its keys (no duplication),
// 16 MFMAs, write 64x16 scores to its private LDS patch (pad 17: 2-way = free),
// scan into per-lane top-4 (lane = query). One combine at block end reduces
// 4 waves' top-4 -> per-chunk top-8 (superset of old per-chunk top-4).
__global__ __launch_bounds__(256) void score_filter_kernel(
    const float* __restrict__ keys, const short* __restrict__ qn_bf,
    float* __restrict__ cand_val, int* __restrict__ cand_idx) {
  __shared__ float slds[4*64*17];          // per-wave patches; reused in combine
  const int bid = blockIdx.x;
  const int chunk = (bid & 7) + 8*(bid >> 6);
  const int gy    = (bid >> 3) & 7;
  if (chunk >= NCHUNK) return;
  const int tid  = threadIdx.x;
  const int wave = tid >> 6, lane = tid & 63;
  const int col  = lane & 15, quad = lane >> 4;

  // A fragments: A[m = query][k], queries qbase..qbase+63, held for whole chunk
  bf8s afrag[4][4];
  const int qbase = gy*64;
  #pragma unroll
  for (int mt = 0; mt < 4; mt++)
    #pragma unroll
    for (int ks = 0; ks < 4; ks++)
      afrag[mt][ks] = *(const bf8s*)(qn_bf + (qbase + mt*16 + col)*KD + ks*32 + quad*8);

  float tv0=-1e30f, tv1=-1e30f, tv2=-1e30f, tv3=-1e30f;
  int   ti0=0, ti1=0, ti2=0, ti3=0;
  const int k0 = chunk*CH + wave*256;      // this wave's private key range

  // prologue: issue tile-0 loads
  f4 x0[4], x1[4];
  {
    int r = k0 + col; if (r > NKEYS-1) r = NKEYS-1;
    const float* kp = keys + (size_t)r*KD + quad*8;
    #pragma unroll
    for (int ks = 0; ks < 4; ks++) {
      x0[ks] = *(const f4*)(kp + ks*32);
      x1[ks] = *(const f4*)(kp + ks*32 + 4);
    }
  }

  #pragma unroll 1
  for (int t16 = 0; t16 < 16; t16++) {
    const int nb = k0 + t16*16;
    // convert current tile: B[k = quad*8+j][n = key col]
    bf8s bfrag[4];
    #pragma unroll
    for (int ks = 0; ks < 4; ks++) {
      bf8s tt;
      tt[0]=(short)f2bf(x0[ks][0]); tt[1]=(short)f2bf(x0[ks][1]);
      tt[2]=(short)f2bf(x0[ks][2]); tt[3]=(short)f2bf(x0[ks][3]);
      tt[4]=(short)f2bf(x1[ks][0]); tt[5]=(short)f2bf(x1[ks][1]);
      tt[6]=(short)f2bf(x1[ks][2]); tt[7]=(short)f2bf(x1[ks][3]);
      bfrag[ks] = tt;
    }
    // issue next tile's loads; they fly under MFMA + LDS + scan (no barriers)
    if (t16 < 15) {
      int r = nb + 16 + col; if (r > NKEYS-1) r = NKEYS-1;
      const float* kp = keys + (size_t)r*KD + quad*8;
      #pragma unroll
      for (int ks = 0; ks < 4; ks++) {
        x0[ks] = *(const f4*)(kp + ks*32);
        x1[ks] = *(const f4*)(kp + ks*32 + 4);
      }
    }
    f4 acc[4];
    #pragma unroll
    for (int mt = 0; mt < 4; mt++) { acc[mt][0]=0.f; acc[mt][1]=0.f; acc[mt][2]=0.f; acc[mt][3]=0.f; }
    #pragma unroll
    for (int ks = 0; ks < 4; ks++)
      #pragma unroll
      for (int mt = 0; mt < 4; mt++)
        acc[mt] = __builtin_amdgcn_mfma_f32_16x16x32_bf16(afrag[mt][ks], bfrag[ks], acc[mt], 0, 0, 0);
    // C/D layout: col = lane&15 (key), row = quad*4 + reg (query) [m89]
    // private patch -> only intra-wave lgkmcnt ordering needed (compiler emits)
    #pragma unroll
    for (int mt = 0; mt < 4; mt++)
      #pragma unroll
      for (int rg = 0; rg < 4; rg++)
        slds[wave*1088 + (mt*16 + quad*4 + rg)*17 + col] = acc[mt][rg];
    // scan: lane owns query (qbase+lane); reads row=lane of its wave's patch
    #pragma unroll
    for (int c = 0; c < 16; c++) {
      int n = nb + c;
      float v = slds[wave*1088 + lane*17 + c];
      if (v > tv3 && n < NKEYS) {
        if (v > tv0)      { tv3=tv2;ti3=ti2; tv2=tv1;ti2=ti1; tv1=tv0;ti1=ti0; tv0=v;ti0=n; }
        else if (v > tv1) { tv3=tv2;ti3=ti2; tv2=tv1;ti2=ti1; tv1=v;ti1=n; }
        else if (v > tv2) { tv3=tv2;ti3=ti2; tv2=v;ti2=n; }
        else              { tv3=v;ti3=n; }
      }
    }
  }

  // ---- block combine: 4 waves x top-4 -> per-query top-8 (2 barriers total)
  __syncthreads();                          // all patch reads done
  float* fv = slds;                         // [4 waves][64 lanes][4]
  int*   fi = (int*)(slds + 1024);
  const int pb = wave*256 + lane*4;
  fv[pb+0]=tv0; fv[pb+1]=tv1; fv[pb+2]=tv2; fv[pb+3]=tv3;
  fi[pb+0]=ti0; fi[pb+1]=ti1; fi[pb+2]=ti2; fi[pb+3]=ti3;
  __syncthreads();
  if (tid < 64) {
    float bv[8]; int bi[8];
    #pragma unroll
    for (int k = 0; k < 8; k++) { bv[k] = -1e30f; bi[k] = 0; }
    #pragma unroll
    for (int w = 0; w < 4; w++)
      #pragma unroll
      for (int j = 0; j < 4; j++) {
        float v = fv[w*256 + tid*4 + j];
        int  ix = fi[w*256 + tid*4 + j];
        if (v > bv[7]) {
          bv[7] = v; bi[7] = ix;
          #pragma unroll
          for (int s = 7; s > 0; s--)
            if (bv[s] > bv[s-1]) {
              float tv = bv[s]; bv[s] = bv[s-1]; bv[s-1] = tv;
              int   ti = bi[s]; bi[s] = bi[s-1]; bi[s-1] = ti;
            }
        }
      }
    const size_t o = ((size_t)(qbase + tid)*NCHUNK + chunk)*CPC;
    f4 v0; v0[0]=bv[0]; v0[1]=bv[1]; v0[2]=bv[2]; v0[3]=bv[3];
    f4 v1; v1[0]=bv[4]; v1[1]=bv[5]; v1[2]=bv[6]; v1[3]=bv[7];
    i4 j0; j0[0]=bi[0]; j0[1]=bi[1]; j0[2]=bi[2]; j0[3]=bi[3];
    i4 j1; j1[0]=bi[4]; j1[1]=bi[5]; j1[2]=bi[6]; j1[3]=bi[7];
    *(f4*)(cand_val + o)     = v0;
    *(f4*)(cand_val + o + 4) = v1;
    *(i4*)(cand_idx + o)     = j0;
    *(i4*)(cand_idx + o + 4) = j1;
  }
}

// ---------------- Kernel 3: radix threshold-select -> exact fp32 rescore ----
__global__ __launch_bounds__(256) void merge_rescore_kernel(
    const float* __restrict__ qn_f, const float* __restrict__ keys,
    const float* __restrict__ values, const float* __restrict__ cand_val,
    const int* __restrict__ cand_idx, float* __restrict__ out) {
  const int b = blockIdx.x, t = threadIdx.x;
  const int lane = t & 63, wave = t >> 6;
  __shared__ float qs[KD];
  __shared__ unsigned hist[256];
  __shared__ int wtot[4];
  __shared__ int s_bound, s_above, s_bcnt, s_cnt;
  __shared__ float rv[CBUF]; __shared__ int ri[CBUF];
  __shared__ float sval[TOPK]; __shared__ int sidx[TOPK]; __shared__ float sw[TOPK];

  if (t < KD) qs[t] = qn_f[b*KD + t];

  // per-thread JCAND candidates, fp32 value -> order-preserving u32
  unsigned u[JCAND]; int id[JCAND];
  #pragma unroll
  for (int j = 0; j < JCAND; j++) {
    int i = t + j*256;
    if (i < NCAND) {
      union { float f; unsigned q; } cvt; cvt.f = cand_val[(size_t)b*NCAND + i];
      unsigned m = cvt.q;
      m = (m & 0x80000000u) ? ~m : (m | 0x80000000u);
      u[j] = m; id[j] = cand_idx[(size_t)b*NCAND + i];
    } else { u[j] = 0u; id[j] = -1; }
  }

  // radix threshold select over top 24 bits, 8 bits per pass
  unsigned prefix = 0; int above = 0; unsigned thr = 0; bool done = false;
  #pragma unroll 1
  for (int pass = 0; pass < 3 && !done; pass++) {
    const int shift = 24 - 8*pass;
    hist[t] = 0u;
    __syncthreads();
    #pragma unroll
    for (int j = 0; j < JCAND; j++) {
      bool ok = (pass == 0) || ((u[j] >> (shift + 8)) == prefix);
      if (ok) atomicAdd(&hist[(u[j] >> shift) & 255u], 1u);
    }
    __syncthreads();
    int h = (int)hist[t];
    int s = h;
    #pragma unroll
    for (int o = 1; o < 64; o <<= 1) {
      int nv = __shfl_down(s, o);
      if (lane + o < 64) s += nv;
    }
    if (lane == 0) wtot[wave] = s;
    __syncthreads();
    int add = 0;
    for (int g = wave + 1; g < 4; g++) add += wtot[g];
    int S = s + add;                          // count of cands with bin >= t
    if (above + S >= 32 && above + S - h < 32) {
      s_bound = t; s_above = above + S - h; s_bcnt = h;
    }
    __syncthreads();
    prefix = (prefix << 8) | (unsigned)s_bound;
    above  = s_above;
    if (s_above + s_bcnt <= CBUF || pass == 2) { thr = prefix << shift; done = true; }
    __syncthreads();
  }

  // collect ids with u >= thr
  if (t == 0) s_cnt = 0;
  __syncthreads();
  #pragma unroll
  for (int j = 0; j < JCAND; j++) {
    if (id[j] >= 0 && u[j] >= thr) {
      int p = atomicAdd(&s_cnt, 1);
      if (p < CBUF) ri[p] = id[j];
    }
  }
  __syncthreads();
  const int C = min(s_cnt, CBUF);
  if (t >= C && t < CBUF) ri[t] = 0x7fffffff;
  __syncthreads();

  // exact fp32 rescore: 4 threads per candidate, 32 dims each
  {
    int c = t >> 2, dg = t & 3;
    float part = 0.f;
    if (c < C) {
      const float* kr = keys + (size_t)ri[c]*KD + dg*32;
      #pragma unroll
      for (int j = 0; j < 32; j++) part += kr[j] * qs[dg*32 + j];
    }
    part += __shfl_down(part, 2, 4);
    part += __shfl_down(part, 1, 4);
    if (dg == 0) rv[c] = (c < C) ? part : -1e30f;
  }
  __syncthreads();

  // exact rank (desc value, tie -> lower index, matching jax.lax.top_k)
  if (t < CBUF) {
    float v = rv[t]; int idx = ri[t];
    int rank = 0;
    for (int j = 0; j < CBUF; j++) {
      float vj = rv[j]; int ij = ri[j];
      rank += (vj > v) || (vj == v && ij < idx);
    }
    if (rank < TOPK) { sval[rank] = v; sidx[rank] = idx; }
  }
  __syncthreads();

  // softmax with +eps denominator; write topw and topidx (as float)
  if (t < TOPK) {
    float m = sval[0];
    float e = expf(sval[t] - m);
    float s2 = e;
    #pragma unroll
    for (int o = 8; o > 0; o >>= 1) s2 += __shfl_down(s2, o, 16);
    s2 = __shfl(s2, 0, 16);
    float w = e / (s2 + 1e-8f);
    sw[t] = w;
    out[NB*VD + b*TOPK + t] = w;                        // topw
    out[NB*VD + NB*TOPK + b*TOPK + t] = (float)sidx[t]; // topidx as float
  }
  __syncthreads();

  // retrieved = sum_k w_k * values[idx_k]
  if (t < VD) {
    float acc = 0.f;
    #pragma unroll
    for (int k = 0; k < TOPK; k++) acc += sw[k] * values[(size_t)sidx[k]*VD + t];
    out[b*VD + t] = acc;
  }
}

extern "C" void kernel_launch(void* const* d_in, const int* in_sizes, int n_in,
                              void* d_out, int out_size, void* d_ws, size_t ws_size,
                              hipStream_t stream) {
  const float* queries = (const float*)d_in[0];
  const float* keys    = (const float*)d_in[1];
  const float* values  = (const float*)d_in[2];
  float* out = (float*)d_out;

  char* ws = (char*)d_ws;
  float* qn_f  = (float*)ws;                                   // 512*128 f32
  short* qn_bf = (short*)(ws + (size_t)NB*KD*4);               // 512*128 bf16
  float* cand_val = (float*)(ws + (size_t)NB*KD*4 + (size_t)NB*KD*2);
  int*   cand_idx = (int*)((char*)cand_val + (size_t)NB*NCAND*sizeof(float));

  qnorm_kernel<<<NB, KD, 0, stream>>>(queries, qn_f, qn_bf);
  // 62*64 = 3968 blocks; 56 tail blocks (chunk>=489) early-exit
  score_filter_kernel<<<62*64, 256, 0, stream>>>(keys, qn_bf, cand_val, cand_idx);
  merge_rescore_kernel<<<NB, 256, 0, stream>>>(qn_f, keys, values, cand_val, cand_idx, out);
}